// Round 1
// 1403.639 us; speedup vs baseline: 1.2248x; 1.2248x over previous
//
#include <hip/hip_runtime.h>
#include <stdint.h>

#define SEQ    512
#define IN_D   128
#define HID    256
#define OUT_D  64

typedef __attribute__((ext_vector_type(8))) short bf16x8;
typedef __attribute__((ext_vector_type(4))) float f32x4;

__device__ __forceinline__ uint16_t f2bf(float f) {
  union { float f; uint32_t u; } v; v.f = f;
  uint32_t r = v.u + 0x7FFFu + ((v.u >> 16) & 1u);
  return (uint16_t)(r >> 16);
}
__device__ __forceinline__ uint32_t packbf(float a, float b) {
  return (uint32_t)f2bf(a) | ((uint32_t)f2bf(b) << 16);
}

// 64-lane sum, all-VALU: 4 DPP steps reduce each 16-lane row (quad xor1,
// quad xor2, row_ror:4, row_ror:8 -- rotations are fixed-point-free so the
// row fully reduces), then 4 readlanes + scalar adds combine the 4 rows.
// Replaces the ds_bpermute-based __shfl_xor butterfly (6 dependent LDS-pipe
// ops ~40cy each) with a ~50-cycle VALU chain. Result is wave-uniform.
__device__ __forceinline__ float wave_sum(float x) {
  x += __int_as_float(__builtin_amdgcn_update_dpp(0, __float_as_int(x), 0xB1, 0xF, 0xF, true));   // quad_perm [1,0,3,2]
  x += __int_as_float(__builtin_amdgcn_update_dpp(0, __float_as_int(x), 0x4E, 0xF, 0xF, true));   // quad_perm [2,3,0,1]
  x += __int_as_float(__builtin_amdgcn_update_dpp(0, __float_as_int(x), 0x124, 0xF, 0xF, true));  // row_ror:4
  x += __int_as_float(__builtin_amdgcn_update_dpp(0, __float_as_int(x), 0x128, 0xF, 0xF, true));  // row_ror:8
  const int xi = __float_as_int(x);
  const float s0 = __int_as_float(__builtin_amdgcn_readlane(xi, 0));
  const float s1 = __int_as_float(__builtin_amdgcn_readlane(xi, 16));
  const float s2 = __int_as_float(__builtin_amdgcn_readlane(xi, 32));
  const float s3 = __int_as_float(__builtin_amdgcn_readlane(xi, 48));
  return (s0 + s1) + (s2 + s3);
}

// acos(x) = sqrt(1-|x|)*poly(|x|), reflected for x<0. |err| ~1e-7 rad.
// Replaces libm acosf's longer dependent chain. Ratio sin(a*th)/sin(th) is
// insensitive to relative theta error at small theta, so this is safe.
__device__ __forceinline__ float fast_acos(float x) {
  const float ax = fabsf(x);
  float p = -0.0012624911f;
  p = p * ax + 0.0066700901f;
  p = p * ax - 0.0170881256f;
  p = p * ax + 0.0308918810f;
  p = p * ax - 0.0501743046f;
  p = p * ax + 0.0889789874f;
  p = p * ax - 0.2145988016f;
  p = p * ax + 1.5707963050f;
  p *= sqrtf(1.0f - ax);
  return (x >= 0.0f) ? p : (3.14159265358979f - p);
}

// LDS-only barrier: waits lgkmcnt(0) (LDS write visibility) but does NOT
// drain vmcnt, so the x prefetch loads and the output global stores stay in
// flight across the barrier (all cross-wave communication is via LDS; global
// ops need no ordering here). asm "memory" clobbers fence IR-level motion,
// sched_barrier(0) fences the backend scheduler (guide rule 18).
__device__ __forceinline__ void lds_barrier() {
  __builtin_amdgcn_sched_barrier(0);
  asm volatile("s_waitcnt lgkmcnt(0)" ::: "memory");
  __builtin_amdgcn_s_barrier();
  asm volatile("" ::: "memory");
  __builtin_amdgcn_sched_barrier(0);
}

// 256 blocks x 512 threads; block handles 8 batch rows for all 512 steps.
// Wave w owns output cols [32w,32w+32) of the fused K=384 GEMM (B-frags in
// regs). Output GEMM (64 cols) is folded into phase A deferred by one step:
// waves 0-3 reuse the in-register ah A-fragments for 8 extra MFMAs and store
// out(t-1); t=511 is handled by an epilogue.
__global__ __launch_bounds__(512, 2) void nlnn_kernel(
    const float* __restrict__ x, const float* __restrict__ h0,
    const float* __restrict__ Win, const float* __restrict__ Wrec,
    const float* __restrict__ Wout, const float* __restrict__ lami,
    const float* __restrict__ lamr, const float* __restrict__ szp,
    const float* __restrict__ araw, float* __restrict__ out) {

  // A-operand staging. Row strides padded (+8 shorts) to break 256B-stride bank aliasing.
  __shared__ __align__(16) short lds_ax[2][16 * 136];  // x_t bf16, double-buffered
  __shared__ __align__(16) short lds_ah[16 * 264];     // h_t bf16 (post-slerp)
  __shared__ __align__(16) float lds_hnew[8 * 256];    // pre-normalize GEMM result fp32

  const int tid = threadIdx.x;
  const int w   = tid >> 6;
  const int l   = tid & 63;
  const int l15 = l & 15;
  const int q   = l >> 4;
  const int blk = blockIdx.x;
  const int row_g = blk * 8 + w;

  // ---- weight B-fragments in registers, lambda folded in ----
  // B-frag layout: lane l holds B[k = 32*kt + 8*(l>>4) + i][col = base + (l&15)]
  bf16x8 wb[12][2];
#pragma unroll
  for (int nt = 0; nt < 2; ++nt) {
    const int col = 32 * w + 16 * nt + l15;
    const float li = lami[col], lr = lamr[col];
#pragma unroll
    for (int kt = 0; kt < 12; ++kt) {
#pragma unroll
      for (int i = 0; i < 8; ++i) {
        const int k = 32 * kt + 8 * q + i;
        const float v = (k < IN_D) ? li * Win[k * HID + col]
                                   : lr * Wrec[(k - IN_D) * HID + col];
        wb[kt][nt][i] = (short)f2bf(v);
      }
    }
  }
  bf16x8 wo[8];
  {
    const float sz = szp[0];  // s_z folded into W_out
    const int col = 16 * (w & 3) + l15;
#pragma unroll
    for (int kt = 0; kt < 8; ++kt)
#pragma unroll
      for (int i = 0; i < 8; ++i) {
        const int k = 32 * kt + 8 * q + i;
        wo[kt][i] = (short)f2bf(sz * Wout[k * OUT_D + col]);
      }
  }

  // alpha = sigmoid(alpha_raw), per-lane cols 4l..4l+3 (same for every wave/row)
  float al[4];
#pragma unroll
  for (int i = 0; i < 4; ++i)
    al[i] = 1.0f / (1.0f + expf(-araw[4 * l + i]));

  // h state: wave w owns row (blk*8+w); lane l holds cols 4l..4l+3 in regs
  float hc[4];
  {
    const f32x4 h4 = *(const f32x4*)&h0[(size_t)row_g * HID + 4 * l];
    hc[0] = h4.x; hc[1] = h4.y; hc[2] = h4.z; hc[3] = h4.w;
    *(uint32_t*)&lds_ah[w * 264 + 4 * l]     = packbf(hc[0], hc[1]);
    *(uint32_t*)&lds_ah[w * 264 + 4 * l + 2] = packbf(hc[2], hc[3]);
  }
  {  // stage x(0)
    const float2 xv = *(const float2*)&x[(size_t)row_g * (SEQ * IN_D) + 2 * l];
    *(uint32_t*)&lds_ax[0][w * 136 + 2 * l] = packbf(xv.x, xv.y);
  }
  // prefetch x(1) into regs (2-deep pipeline: load issued one full iteration
  // before its LDS staging, so HBM latency is always covered)
  float2 xn = *(const float2*)&x[((size_t)row_g * SEQ + 1) * IN_D + 2 * l];
  lds_barrier();

  for (int t = 0; t < SEQ; ++t) {
    const int p = t & 1;

    // stage x(t+1) from regs loaded last iteration; then issue load of x(t+2)
    *(uint32_t*)&lds_ax[p ^ 1][w * 136 + 2 * l] = packbf(xn.x, xn.y);
    {
      const int tn = (t + 2 < SEQ) ? t + 2 : SEQ - 1;
      xn = *(const float2*)&x[((size_t)row_g * SEQ + tn) * IN_D + 2 * l];
    }

    // ---- phase A: fused [x|h] @ [li*Win; lr*Wrec], M=16 (rows 0-7 real) ----
    f32x4 acc0 = {0.f, 0.f, 0.f, 0.f};
    f32x4 acc1 = {0.f, 0.f, 0.f, 0.f};
    const short* ax = &lds_ax[p][l15 * 136 + 8 * q];
    const short* ah = &lds_ah[l15 * 264 + 8 * q];
#pragma unroll
    for (int kt = 0; kt < 4; ++kt) {
      bf16x8 a = *(const bf16x8*)(ax + 32 * kt);
      acc0 = __builtin_amdgcn_mfma_f32_16x16x32_bf16(a, wb[kt][0], acc0, 0, 0, 0);
      acc1 = __builtin_amdgcn_mfma_f32_16x16x32_bf16(a, wb[kt][1], acc1, 0, 0, 0);
    }
    bf16x8 af[8];  // keep h-fragments in regs: reused by the folded out-GEMM
#pragma unroll
    for (int kt = 0; kt < 8; ++kt) {
      af[kt] = *(const bf16x8*)(ah + 32 * kt);
      acc0 = __builtin_amdgcn_mfma_f32_16x16x32_bf16(af[kt], wb[4 + kt][0], acc0, 0, 0, 0);
      acc1 = __builtin_amdgcn_mfma_f32_16x16x32_bf16(af[kt], wb[4 + kt][1], acc1, 0, 0, 0);
    }
    // D-layout: col = lane&15, row = 4*(lane>>4)+reg -> rows 0-7 live in lanes 0-31
    if (l < 32) {
      const int colb = 32 * w + l15;
      const int r0 = 4 * q;
#pragma unroll
      for (int i = 0; i < 4; ++i) {
        lds_hnew[(r0 + i) * HID + colb]      = acc0[i];
        lds_hnew[(r0 + i) * HID + colb + 16] = acc1[i];
      }
    }
    // folded output GEMM: out(t-1) = s_z*(h(t-1) @ Wout); lds_ah holds h(t-1)
    if (w < 4) {
      f32x4 ao = {0.f, 0.f, 0.f, 0.f};
#pragma unroll
      for (int kt = 0; kt < 8; ++kt)
        ao = __builtin_amdgcn_mfma_f32_16x16x32_bf16(af[kt], wo[kt], ao, 0, 0, 0);
      if (t > 0 && l < 32) {
        const int col = 16 * w + l15;
        const int r0 = 4 * q;
#pragma unroll
        for (int i = 0; i < 4; ++i)
          out[((size_t)(blk * 8 + r0 + i) * SEQ + (t - 1)) * OUT_D + col] = ao[i];
      }
    }
    lds_barrier();

    // ---- phase B: normalize + slerp; wave w = row w, lane l = cols 4l..4l+3 ----
    const f32x4 hn4 = *(const f32x4*)&lds_hnew[w * HID + 4 * l];
    float hn[4] = {hn4.x, hn4.y, hn4.z, hn4.w};
    float ssp = hn[0]*hn[0] + hn[1]*hn[1] + hn[2]*hn[2] + hn[3]*hn[3];
    float dtp = hc[0]*hn[0] + hc[1]*hn[1] + hc[2]*hn[2] + hc[3]*hn[3];
    const float ss = wave_sum(ssp);
    const float dtt = wave_sum(dtp);
    const float invn = 1.0f / (sqrtf(ss) + 1e-8f);
    float d = dtt * invn;                      // dot(h_t, h_new_normalized)
    d = fminf(fmaxf(d, -1.0f), 1.0f);          // clip(+-1e-8) is identity in fp32
    const float th = fast_acos(d);
    const float st = __sinf(th);
    const bool msk = st > 1e-8f;
    const float den = 1.0f / (st + 1e-8f);
    float res[4]; float s2p = 0.f;
#pragma unroll
    for (int i = 0; i < 4; ++i) {
      const float hni = hn[i] * invn;
      const float ct = __sinf((1.0f - al[i]) * th) * den;
      const float cn = __sinf(al[i] * th) * den;
      const float r = msk ? (ct * hc[i] + cn * hni) : hni;
      res[i] = r; s2p += r * r;
    }
    const float s2 = wave_sum(s2p);
    const float inv2 = 1.0f / (sqrtf(s2) + 1e-8f);
#pragma unroll
    for (int i = 0; i < 4; ++i) hc[i] = res[i] * inv2;
    *(uint32_t*)&lds_ah[w * 264 + 4 * l]     = packbf(hc[0], hc[1]);
    *(uint32_t*)&lds_ah[w * 264 + 4 * l + 2] = packbf(hc[2], hc[3]);
    lds_barrier();
  }

  // ---- epilogue: out(511) from the final post-slerp h in lds_ah ----
  if (w < 4) {
    f32x4 ao = {0.f, 0.f, 0.f, 0.f};
    const short* ah2 = &lds_ah[l15 * 264 + 8 * q];
#pragma unroll
    for (int kt = 0; kt < 8; ++kt) {
      bf16x8 a = *(const bf16x8*)(ah2 + 32 * kt);
      ao = __builtin_amdgcn_mfma_f32_16x16x32_bf16(a, wo[kt], ao, 0, 0, 0);
    }
    if (l < 32) {
      const int col = 16 * w + l15;
      const int r0 = 4 * q;
#pragma unroll
      for (int i = 0; i < 4; ++i)
        out[((size_t)(blk * 8 + r0 + i) * SEQ + (SEQ - 1)) * OUT_D + col] = ao[i];
    }
  }

  // h_fin, appended after outs
  float* hf = out + (size_t)2048 * SEQ * OUT_D;
  f32x4 hv; hv.x = hc[0]; hv.y = hc[1]; hv.z = hc[2]; hv.w = hc[3];
  *(f32x4*)&hf[(size_t)row_g * HID + 4 * l] = hv;
}

extern "C" void kernel_launch(void* const* d_in, const int* in_sizes, int n_in,
                              void* d_out, int out_size, void* d_ws, size_t ws_size,
                              hipStream_t stream) {
  const float* x    = (const float*)d_in[0];
  const float* h0   = (const float*)d_in[1];
  const float* Win  = (const float*)d_in[2];
  const float* Wrec = (const float*)d_in[3];
  const float* Wout = (const float*)d_in[4];
  const float* li   = (const float*)d_in[5];
  const float* lr   = (const float*)d_in[6];
  const float* sz   = (const float*)d_in[7];
  const float* ar   = (const float*)d_in[8];
  nlnn_kernel<<<256, 512, 0, stream>>>(x, h0, Win, Wrec, Wout, li, lr, sz, ar,
                                       (float*)d_out);
}